// Round 1
// baseline (487.719 us; speedup 1.0000x reference)
//
#include <hip/hip_runtime.h>
#include <hip/hip_bf16.h>

typedef __bf16 bf16x8 __attribute__((ext_vector_type(8)));
typedef float f32x4 __attribute__((ext_vector_type(4)));
typedef unsigned short u16;
typedef unsigned int u32;
typedef unsigned long long u64;

// B=32, L=1024, D=1024, H=8, E=128, M=64 (modes), M2=128 (re+im rows)

static __device__ __forceinline__ u16 f2b(float f) {
  u32 u = __builtin_bit_cast(u32, f);
  u32 r = (u + 0x7FFFu + ((u >> 16) & 1u)) >> 16;
  return (u16)r;
}
static __device__ __forceinline__ float b2f(u16 s) {
  u32 u = ((u32)s) << 16;
  return __builtin_bit_cast(float, u);
}
static __device__ __forceinline__ f32x4 mfma16(bf16x8 a, bf16x8 b, f32x4 c) {
  return __builtin_amdgcn_mfma_f32_16x16x32_bf16(a, b, c, 0, 0, 0);
}

// ---------------- prep: DFT tables (bf16) + Wq/Wo -> bf16 ----------------
__global__ __launch_bounds__(256) void k_prep(
    const float* __restrict__ Wq, const float* __restrict__ Wo,
    u16* __restrict__ FT, u16* __restrict__ FI,
    u16* __restrict__ Wq16, u16* __restrict__ Wo16) {
  int idx = blockIdx.x * 256 + threadIdx.x;
  const float W0 = 6.283185307179586f / 1024.0f;
  if (idx < 131072) {                       // FT[m2][l]: rfft basis rows
    int m2 = idx >> 10, l = idx & 1023;
    int m = (m2 < 64) ? m2 : (m2 - 64);
    int t = (m * l) & 1023;
    float s, c;
    __sincosf((float)t * W0, &s, &c);
    FT[idx] = f2b((m2 < 64) ? c : -s);      // X_re = sum q*cos ; X_im = sum q*(-sin)
  } else if (idx < 262144) {                // FI[m2][l]: irfft basis rows
    int j = idx - 131072;
    int m2 = j >> 10, l = j & 1023;
    int m = (m2 < 64) ? m2 : (m2 - 64);
    int t = (m * l) & 1023;
    float s, c;
    __sincosf((float)t * W0, &s, &c);
    float v;
    if (m2 == 0) v = 1.0f / 1024.0f;
    else if (m2 < 64) v = c * (2.0f / 1024.0f);
    else if (m2 == 64) v = 0.0f;            // imag of DC ignored by irfft
    else v = -s * (2.0f / 1024.0f);
    FI[j] = f2b(v);
  } else if (idx < 262144 + 1048576) {
    int k = idx - 262144;
    Wq16[k] = f2b(Wq[k]);
  } else {
    int k = idx - 1310720;
    Wo16[k] = f2b(Wo[k]);
  }
}

// ------------- w1 transpose: [h][e][o][m] f32 -> [h][m][e][o] bf16 -------------
__global__ __launch_bounds__(256) void k_wtrans(
    const float* __restrict__ w1r, const float* __restrict__ w1i,
    u16* __restrict__ W2r, u16* __restrict__ W2i) {
  __shared__ float T[128 * 65];
  int h = blockIdx.x >> 7, e = blockIdx.x & 127;
  int tid = threadIdx.x;
  for (int pass = 0; pass < 2; ++pass) {
    const float* src = pass ? w1i : w1r;
    u16* dst = pass ? W2i : W2r;
    {
      int m = tid & 63, og = tid >> 6;
      const float* sp = src + (((size_t)h * 128 + e) * 128) * 64 + m;
      for (int k = 0; k < 32; ++k) {
        int o = og * 32 + k;
        T[o * 65 + m] = sp[(size_t)o * 64];
      }
    }
    __syncthreads();
    {
      int o = tid & 127, mg = tid >> 7;
      for (int k = 0; k < 32; ++k) {
        int m = mg * 32 + k;
        dst[(((size_t)h * 64 + m) * 128 + e) * 128 + o] = f2b(T[o * 65 + m]);
      }
    }
    __syncthreads();
  }
}

// ---------------- generic 128x128-tile bf16 GEMM body ----------------
// C[crow0+r][bcol0+c] = sum_k A[arow0+r][k] * Bm[k][bcol0+c]
// A row-major (stride astride, k contiguous), Bm row-major [k][1024].
template <int KSTEPS, bool BIAS>
static __device__ __forceinline__ void gemm128(
    const u16* __restrict__ A, size_t arow0, int astride,
    const u16* __restrict__ Bm, int bcol0,
    u16* __restrict__ C, size_t crow0, const float* __restrict__ bias) {
  __shared__ __align__(16) u16 Al[128 * 40];
  __shared__ __align__(16) u16 Bl[128 * 40];
  int tid = threadIdx.x, lane = tid & 63, w = tid >> 6;
  f32x4 acc[2][8];
#pragma unroll
  for (int i = 0; i < 2; i++)
#pragma unroll
    for (int j = 0; j < 8; j++) acc[i][j] = (f32x4){0.f, 0.f, 0.f, 0.f};
  int ar = tid >> 1, ahalf = tid & 1;
  int dloc = tid & 127, lg = tid >> 7;
  for (int kk = 0; kk < KSTEPS; ++kk) {
    {  // A tile [128][32], k-contiguous -> vector copy
      const uint4* src = (const uint4*)(A + (arow0 + ar) * (size_t)astride + kk * 32 + ahalf * 16);
      uint4 v0 = src[0], v1 = src[1];
      uint4* dst = (uint4*)(Al + ar * 40 + ahalf * 16);
      dst[0] = v0; dst[1] = v1;
    }
    {  // B tile: global [k][n] -> LDS [n][k] (reg transpose, 4-packs)
#pragma unroll
      for (int jj = 0; jj < 4; ++jj) {
        int l0 = lg * 16 + jj * 4;
        const u16* bp = Bm + (size_t)(kk * 32 + l0) * 1024 + bcol0 + dloc;
        u16 s0 = bp[0], s1 = bp[1024], s2 = bp[2048], s3 = bp[3072];
        *(u64*)(Bl + dloc * 40 + l0) =
            (u64)s0 | ((u64)s1 << 16) | ((u64)s2 << 32) | ((u64)s3 << 48);
      }
    }
    __syncthreads();
    bf16x8 af[2];
#pragma unroll
    for (int mi = 0; mi < 2; mi++)
      af[mi] = *(const bf16x8*)(Al + (w * 32 + mi * 16 + (lane & 15)) * 40 + 8 * (lane >> 4));
#pragma unroll
    for (int ni = 0; ni < 8; ni++) {
      bf16x8 bf = *(const bf16x8*)(Bl + (ni * 16 + (lane & 15)) * 40 + 8 * (lane >> 4));
#pragma unroll
      for (int mi = 0; mi < 2; mi++) acc[mi][ni] = mfma16(af[mi], bf, acc[mi][ni]);
    }
    __syncthreads();
  }
  if (BIAS) {  // += L*bq on local row 0 (mode-0 real row)
    if (w == 0 && (lane >> 4) == 0) {
#pragma unroll
      for (int ni = 0; ni < 8; ni++)
        acc[0][ni][0] += 1024.0f * bias[bcol0 + ni * 16 + (lane & 15)];
    }
  }
#pragma unroll
  for (int mi = 0; mi < 2; mi++)
#pragma unroll
    for (int ni = 0; ni < 8; ni++)
#pragma unroll
      for (int r = 0; r < 4; r++) {
        int row = w * 32 + mi * 16 + 4 * (lane >> 4) + r;
        int col = bcol0 + ni * 16 + (lane & 15);
        C[(crow0 + row) * (size_t)1024 + col] = f2b(acc[mi][ni][r]);
      }
}

// ---------------- DFT: Z[b][m2][c] = sum_l FT[m2][l] * x[b][l][c] ----------------
__global__ __launch_bounds__(256) void k_dft(const float* __restrict__ x,
                                             const u16* __restrict__ FT,
                                             u16* __restrict__ Z) {
  __shared__ __align__(16) u16 Al[128 * 40];
  __shared__ __align__(16) u16 Bl[128 * 40];
  int b = blockIdx.x >> 3, ct = blockIdx.x & 7;
  int tid = threadIdx.x, lane = tid & 63, w = tid >> 6;
  f32x4 acc[2][8];
#pragma unroll
  for (int i = 0; i < 2; i++)
#pragma unroll
    for (int j = 0; j < 8; j++) acc[i][j] = (f32x4){0.f, 0.f, 0.f, 0.f};
  int am2 = tid >> 1, ahalf = tid & 1;
  int c = tid & 127, lg = tid >> 7;
  for (int kk = 0; kk < 32; ++kk) {
    {
      const uint4* src = (const uint4*)(FT + am2 * 1024 + kk * 32 + ahalf * 16);
      uint4 v0 = src[0], v1 = src[1];
      uint4* dst = (uint4*)(Al + am2 * 40 + ahalf * 16);
      dst[0] = v0; dst[1] = v1;
    }
    {
      const float* xb = x + ((size_t)b * 1024 + kk * 32) * 1024 + ct * 128 + c;
#pragma unroll
      for (int jj = 0; jj < 4; ++jj) {
        int l0 = lg * 16 + jj * 4;
        float f0 = xb[(size_t)(l0 + 0) * 1024];
        float f1 = xb[(size_t)(l0 + 1) * 1024];
        float f2_ = xb[(size_t)(l0 + 2) * 1024];
        float f3 = xb[(size_t)(l0 + 3) * 1024];
        *(u64*)(Bl + c * 40 + l0) = (u64)f2b(f0) | ((u64)f2b(f1) << 16) |
                                    ((u64)f2b(f2_) << 32) | ((u64)f2b(f3) << 48);
      }
    }
    __syncthreads();
    bf16x8 af[2];
#pragma unroll
    for (int mi = 0; mi < 2; mi++)
      af[mi] = *(const bf16x8*)(Al + (w * 32 + mi * 16 + (lane & 15)) * 40 + 8 * (lane >> 4));
#pragma unroll
    for (int ni = 0; ni < 8; ni++) {
      bf16x8 bf = *(const bf16x8*)(Bl + (ni * 16 + (lane & 15)) * 40 + 8 * (lane >> 4));
#pragma unroll
      for (int mi = 0; mi < 2; mi++) acc[mi][ni] = mfma16(af[mi], bf, acc[mi][ni]);
    }
    __syncthreads();
  }
#pragma unroll
  for (int mi = 0; mi < 2; mi++)
#pragma unroll
    for (int ni = 0; ni < 8; ni++)
#pragma unroll
      for (int r = 0; r < 4; r++) {
        int row = w * 32 + mi * 16 + 4 * (lane >> 4) + r;
        int col = ct * 128 + ni * 16 + (lane & 15);
        Z[((size_t)b * 128 + row) * 1024 + col] = f2b(acc[mi][ni][r]);
      }
}

__global__ __launch_bounds__(256) void k_wqmix(const u16* __restrict__ Zm,
                                               const u16* __restrict__ Wq16,
                                               const float* __restrict__ bq,
                                               u16* __restrict__ XF) {
  int mt = blockIdx.x >> 3, nt = blockIdx.x & 7;
  gemm128<32, true>(Zm, (size_t)mt * 128, 1024, Wq16, nt * 128, XF, (size_t)mt * 128, bq);
}

__global__ __launch_bounds__(256) void k_gmat(const u16* __restrict__ FI,
                                              const u16* __restrict__ Wo16,
                                              u16* __restrict__ G) {
  int nt = blockIdx.x;
  gemm128<32, false>(FI, 0, 1024, Wo16, nt * 128, G, 0, nullptr);
}

// ------- mode mix per (h,m): complex [32b x 128e] @ [128e x 128o], writes OS2T -------
__global__ __launch_bounds__(256) void k_modemix(const u16* __restrict__ XF,
                                                 const u16* __restrict__ W2r,
                                                 const u16* __restrict__ W2i,
                                                 u16* __restrict__ OS2T) {
  __shared__ __align__(16) u16 XAr[32 * 200], XAi[32 * 200];
  __shared__ __align__(16) u16 Wbr[128 * 40], Wbi[128 * 40];
  int h = blockIdx.x >> 6, m = blockIdx.x & 63;
  int tid = threadIdx.x, lane = tid & 63, w = tid >> 6;
  {  // stage XF rows (re: m2=m, im: m2=64+m) for this h: [32b][128e]
    int bb = tid >> 3, seg = tid & 7;
    int e0 = seg * 16, kc = seg >> 1, off = (seg & 1) * 16;
    const uint4* sr = (const uint4*)(XF + ((size_t)bb * 128 + m) * 1024 + h * 128 + e0);
    const uint4* si = (const uint4*)(XF + ((size_t)bb * 128 + 64 + m) * 1024 + h * 128 + e0);
    uint4* dr = (uint4*)(XAr + bb * 200 + kc * 40 + off);
    uint4* di = (uint4*)(XAi + bb * 200 + kc * 40 + off);
    dr[0] = sr[0]; dr[1] = sr[1];
    di[0] = si[0]; di[1] = si[1];
  }
  f32x4 accR[2][2], accI[2][2];
#pragma unroll
  for (int i = 0; i < 2; i++)
#pragma unroll
    for (int j = 0; j < 2; j++) {
      accR[i][j] = (f32x4){0.f, 0.f, 0.f, 0.f};
      accI[i][j] = (f32x4){0.f, 0.f, 0.f, 0.f};
    }
  for (int kk = 0; kk < 4; ++kk) {
    {  // stage W2r/W2i [e-chunk 32][o 128] -> LDS [o][e]
      int o = tid & 127, pr = tid >> 7;
      const u16* src = (pr ? W2i : W2r) + (((size_t)h * 64 + m) * 128 + kk * 32) * 128 + o;
      u16* dst = (pr ? Wbi : Wbr) + o * 40;
#pragma unroll
      for (int jj = 0; jj < 8; ++jj) {
        int e0 = jj * 4;
        u16 s0 = src[(size_t)(e0 + 0) * 128], s1 = src[(size_t)(e0 + 1) * 128];
        u16 s2 = src[(size_t)(e0 + 2) * 128], s3 = src[(size_t)(e0 + 3) * 128];
        *(u64*)(dst + e0) = (u64)s0 | ((u64)s1 << 16) | ((u64)s2 << 32) | ((u64)s3 << 48);
      }
    }
    __syncthreads();
    bf16x8 ar[2], ai_[2], ain[2];
#pragma unroll
    for (int mi = 0; mi < 2; mi++) {
      int bb = mi * 16 + (lane & 15);
      ar[mi] = *(const bf16x8*)(XAr + bb * 200 + kk * 40 + 8 * (lane >> 4));
      ai_[mi] = *(const bf16x8*)(XAi + bb * 200 + kk * 40 + 8 * (lane >> 4));
      u32 t4[4];
      __builtin_memcpy(t4, &ai_[mi], 16);
#pragma unroll
      for (int q = 0; q < 4; q++) t4[q] ^= 0x80008000u;
      __builtin_memcpy(&ain[mi], t4, 16);
    }
#pragma unroll
    for (int ni = 0; ni < 2; ni++) {
      int o = w * 32 + ni * 16 + (lane & 15);
      bf16x8 br = *(const bf16x8*)(Wbr + o * 40 + 8 * (lane >> 4));
      bf16x8 bi = *(const bf16x8*)(Wbi + o * 40 + 8 * (lane >> 4));
#pragma unroll
      for (int mi = 0; mi < 2; mi++) {
        accR[mi][ni] = mfma16(ar[mi], br, accR[mi][ni]);
        accR[mi][ni] = mfma16(ain[mi], bi, accR[mi][ni]);  // - Xi*Wi
        accI[mi][ni] = mfma16(ar[mi], bi, accI[mi][ni]);
        accI[mi][ni] = mfma16(ai_[mi], br, accI[mi][ni]);
      }
    }
    __syncthreads();
  }
#pragma unroll
  for (int mi = 0; mi < 2; mi++)
#pragma unroll
    for (int ni = 0; ni < 2; ni++)
#pragma unroll
      for (int rr = 0; rr < 4; rr++) {
        int brow = mi * 16 + 4 * (lane >> 4) + rr;  // batch index
        int o = w * 32 + ni * 16 + (lane & 15);
        size_t base = (size_t)brow * 131072 + (size_t)(h * 128 + o) * 128;
        OS2T[base + m] = f2b(accR[mi][ni][rr]);
        OS2T[base + 64 + m] = f2b(accI[mi][ni][rr]);
      }
}

// ---- output GEMM: NX[b][l'][d] = sum_m2 OS2T[b][l'][m2] * G[m2][d]  (K=128) ----
__global__ __launch_bounds__(256) void k_osg(const u16* __restrict__ OS2T,
                                             const u16* __restrict__ G,
                                             u16* __restrict__ NX) {
  int b = blockIdx.x >> 6, t6 = blockIdx.x & 63;
  int mt = t6 >> 3, nt = t6 & 7;
  gemm128<4, false>(OS2T, (size_t)b * 1024 + mt * 128, 128, G, nt * 128, NX,
                    (size_t)b * 1024 + mt * 128, nullptr);
}

// ------- residual + series_decomp: res = z - MA25(z), z = x + NX (bo cancels) -------
__global__ __launch_bounds__(256) void k_decomp(const float* __restrict__ x,
                                                const u16* __restrict__ NX,
                                                float* __restrict__ out) {
  __shared__ float ZT[280 * 64];
  int b = blockIdx.x >> 6, r6 = blockIdx.x & 63;
  int lc = r6 >> 4, dt = r6 & 15;
  int tid = threadIdx.x, dl = tid & 63;
  int l0 = lc * 256, dbase = dt * 64;
  for (int r = tid >> 6; r < 280; r += 4) {
    int gl = l0 + r - 12;
    gl = gl < 0 ? 0 : (gl > 1023 ? 1023 : gl);
    size_t gi = ((size_t)b * 1024 + gl) * 1024 + dbase + dl;
    ZT[r * 64 + dl] = x[gi] + b2f(NX[gi]);
  }
  __syncthreads();
  int sub = tid >> 6;
  int base = sub * 64;
  float s = 0.0f;
#pragma unroll
  for (int j = 0; j < 25; ++j) s += ZT[(base + j) * 64 + dl];
  for (int i = 0; i < 64; ++i) {
    float center = ZT[(base + i + 12) * 64 + dl];
    size_t oi = ((size_t)b * 1024 + l0 + base + i) * 1024 + dbase + dl;
    out[oi] = center - s * (1.0f / 25.0f);
    if (i < 63) s += ZT[(base + i + 25) * 64 + dl] - ZT[(base + i) * 64 + dl];
  }
}

extern "C" void kernel_launch(void* const* d_in, const int* in_sizes, int n_in,
                              void* d_out, int out_size, void* d_ws, size_t ws_size,
                              hipStream_t stream) {
  const float* x = (const float*)d_in[0];
  const float* Wq = (const float*)d_in[1];
  const float* bq = (const float*)d_in[2];
  const float* w1r = (const float*)d_in[3];
  const float* w1i = (const float*)d_in[4];
  const float* Wo = (const float*)d_in[5];
  // d_in[6] = bo: exactly cancels in res = z - MA(z) (constant along L, replicate pad)

  char* ws = (char*)d_ws;
  u16* FT = (u16*)(ws + 0x000000);      // 256 KB  [128][1024]
  u16* FI = (u16*)(ws + 0x040000);      // 256 KB  [128][1024]
  u16* Wq16 = (u16*)(ws + 0x080000);    // 2 MB
  u16* Wo16 = (u16*)(ws + 0x280000);    // 2 MB
  u16* G = (u16*)(ws + 0x480000);       // 256 KB  [128][1024]
  u16* NX = (u16*)(ws + 0x500000);      // 64 MB   [32][1024][1024] bf16

  // Scratch dead before k_decomp lives in d_out (134 MB, fully rewritten by k_decomp)
  char* ob = (char*)d_out;
  u16* W2r = (u16*)(ob + 0x0000000);    // 16.8 MB [h][m][e][o]
  u16* W2i = (u16*)(ob + 0x1000000);    // 16.8 MB
  u16* Zm = (u16*)(ob + 0x2000000);     // 8.4 MB  [b][m2][1024]
  u16* XF = (u16*)(ob + 0x2800000);     // 8.4 MB  [b*128+m2][1024]
  u16* OS2T = (u16*)(ob + 0x3000000);   // 8.4 MB  [b][d'][m2]

  k_prep<<<9216, 256, 0, stream>>>(Wq, Wo, FT, FI, Wq16, Wo16);
  k_wtrans<<<1024, 256, 0, stream>>>(w1r, w1i, W2r, W2i);
  k_gmat<<<8, 256, 0, stream>>>(FI, Wo16, G);
  k_dft<<<256, 256, 0, stream>>>(x, FT, Zm);
  k_wqmix<<<256, 256, 0, stream>>>(Zm, Wq16, bq, XF);
  k_modemix<<<512, 256, 0, stream>>>(XF, W2r, W2i, OS2T);
  k_osg<<<2048, 256, 0, stream>>>(OS2T, G, NX);
  k_decomp<<<2048, 256, 0, stream>>>(x, NX, (float*)d_out);
}

// Round 5
// 429.387 us; speedup vs baseline: 1.1358x; 1.1358x over previous
//
#include <hip/hip_runtime.h>
#include <hip/hip_bf16.h>

typedef __bf16 bf16x8 __attribute__((ext_vector_type(8)));
typedef float f32x4 __attribute__((ext_vector_type(4)));
typedef unsigned short u16;
typedef unsigned int u32;
typedef unsigned long long u64;

// B=32, L=1024, D=1024, H=8, E=128, M=64 modes. M2=128 (re/im interleaved in G2/OS2T).

static __device__ __forceinline__ u16 f2b(float f) {
  u32 u = __builtin_bit_cast(u32, f);
  u32 r = (u + 0x7FFFu + ((u >> 16) & 1u)) >> 16;
  return (u16)r;
}
static __device__ __forceinline__ float b2f(u16 s) {
  u32 u = ((u32)s) << 16;
  return __builtin_bit_cast(float, u);
}
static __device__ __forceinline__ u32 pk2(float lo, float hi) {
  return (u32)f2b(lo) | ((u32)f2b(hi) << 16);
}
static __device__ __forceinline__ f32x4 mfma16(bf16x8 a, bf16x8 b, f32x4 c) {
  return __builtin_amdgcn_mfma_f32_16x16x32_bf16(a, b, c, 0, 0, 0);
}

// ---------------- prep: DFT tables (bf16) + Wq/Wo -> bf16 ----------------
// FI2 rows interleaved: row 2m = cos-basis (irfft), row 2m+1 = -sin-basis.
__global__ __launch_bounds__(256) void k_prep(
    const float* __restrict__ Wq, const float* __restrict__ Wo,
    u16* __restrict__ FT, u16* __restrict__ FI2,
    u16* __restrict__ Wq16, u16* __restrict__ Wo16) {
  int idx = blockIdx.x * 256 + threadIdx.x;
  const float W0 = 6.283185307179586f / 1024.0f;
  if (idx < 131072) {                       // FT[m2][l]: rfft rows (0..63 re, 64..127 im)
    int m2 = idx >> 10, l = idx & 1023;
    int m = (m2 < 64) ? m2 : (m2 - 64);
    int t = (m * l) & 1023;
    float s, c;
    __sincosf((float)t * W0, &s, &c);
    FT[idx] = f2b((m2 < 64) ? c : -s);
  } else if (idx < 262144) {                // FI2[j][l], j = 2m (+1 for imag)
    int jj = idx - 131072;
    int j = jj >> 10, l = jj & 1023;
    int m = j >> 1;
    int t = (m * l) & 1023;
    float s, c;
    __sincosf((float)t * W0, &s, &c);
    float v;
    if ((j & 1) == 0) v = (m == 0) ? (1.0f / 1024.0f) : c * (2.0f / 1024.0f);
    else              v = (m == 0) ? 0.0f : -s * (2.0f / 1024.0f);
    FI2[jj] = f2b(v);
  } else if (idx < 262144 + 1048576) {
    int k = idx - 262144;
    Wq16[k] = f2b(Wq[k]);
  } else {
    int k = idx - 1310720;
    Wo16[k] = f2b(Wo[k]);
  }
}

// ------------- w1 transpose: [h][e][o][m] f32 -> [h][m][e][o] bf16 -------------
__global__ __launch_bounds__(256) void k_wtrans(
    const float* __restrict__ w1r, const float* __restrict__ w1i,
    u16* __restrict__ W2r, u16* __restrict__ W2i) {
  __shared__ float T[128 * 65];
  int h = blockIdx.x >> 7, e = blockIdx.x & 127;
  int tid = threadIdx.x;
  for (int pass = 0; pass < 2; ++pass) {
    const float* src = pass ? w1i : w1r;
    u16* dst = pass ? W2i : W2r;
    {
      int m = tid & 63, og = tid >> 6;
      const float* sp = src + (((size_t)h * 128 + e) * 128) * 64 + m;
      for (int k = 0; k < 32; ++k) {
        int o = og * 32 + k;
        T[o * 65 + m] = sp[(size_t)o * 64];
      }
    }
    __syncthreads();
    {
      int o = tid & 127, mg = tid >> 7;
      for (int k = 0; k < 32; ++k) {
        int m = mg * 32 + k;
        dst[(((size_t)h * 64 + m) * 128 + e) * 128 + o] = f2b(T[o * 65 + m]);
      }
    }
    __syncthreads();
  }
}

// ---------------- generic 128x128-tile bf16 GEMM body (K = 32*KSTEPS) ----------------
template <int KSTEPS, bool BIAS>
static __device__ __forceinline__ void gemm128(
    const u16* __restrict__ A, size_t arow0, int astride,
    const u16* __restrict__ Bm, int bcol0,
    u16* __restrict__ C, size_t crow0, const float* __restrict__ bias) {
  __shared__ __align__(16) u16 Al[128 * 40];
  __shared__ __align__(16) u16 Bl[128 * 40];
  int tid = threadIdx.x, lane = tid & 63, w = tid >> 6;
  f32x4 acc[2][8];
#pragma unroll
  for (int i = 0; i < 2; i++)
#pragma unroll
    for (int j = 0; j < 8; j++) acc[i][j] = (f32x4){0.f, 0.f, 0.f, 0.f};
  int ar = tid >> 1, ahalf = tid & 1;
  int dloc = tid & 127, lg = tid >> 7;
  for (int kk = 0; kk < KSTEPS; ++kk) {
    {
      const uint4* src = (const uint4*)(A + (arow0 + ar) * (size_t)astride + kk * 32 + ahalf * 16);
      uint4 v0 = src[0], v1 = src[1];
      uint4* dst = (uint4*)(Al + ar * 40 + ahalf * 16);
      dst[0] = v0; dst[1] = v1;
    }
    {
#pragma unroll
      for (int jj = 0; jj < 4; ++jj) {
        int l0 = lg * 16 + jj * 4;
        const u16* bp = Bm + (size_t)(kk * 32 + l0) * 1024 + bcol0 + dloc;
        u16 s0 = bp[0], s1 = bp[1024], s2 = bp[2048], s3 = bp[3072];
        *(u64*)(Bl + dloc * 40 + l0) =
            (u64)s0 | ((u64)s1 << 16) | ((u64)s2 << 32) | ((u64)s3 << 48);
      }
    }
    __syncthreads();
    bf16x8 af[2];
#pragma unroll
    for (int mi = 0; mi < 2; mi++)
      af[mi] = *(const bf16x8*)(Al + (w * 32 + mi * 16 + (lane & 15)) * 40 + 8 * (lane >> 4));
#pragma unroll
    for (int ni = 0; ni < 8; ni++) {
      bf16x8 bf = *(const bf16x8*)(Bl + (ni * 16 + (lane & 15)) * 40 + 8 * (lane >> 4));
#pragma unroll
      for (int mi = 0; mi < 2; mi++) acc[mi][ni] = mfma16(af[mi], bf, acc[mi][ni]);
    }
    __syncthreads();
  }
  if (BIAS) {  // += L*bq on local row 0 (mode-0 real row of XF)
    if (w == 0 && (lane >> 4) == 0) {
#pragma unroll
      for (int ni = 0; ni < 8; ni++)
        acc[0][ni][0] += 1024.0f * bias[bcol0 + ni * 16 + (lane & 15)];
    }
  }
#pragma unroll
  for (int mi = 0; mi < 2; mi++)
#pragma unroll
    for (int ni = 0; ni < 8; ni++)
#pragma unroll
      for (int r = 0; r < 4; r++) {
        int row = w * 32 + mi * 16 + 4 * (lane >> 4) + r;
        int col = bcol0 + ni * 16 + (lane & 15);
        C[(crow0 + row) * (size_t)1024 + col] = f2b(acc[mi][ni][r]);
      }
}

// ---------------- DFT: Z[b][m2][c] = sum_l FT[m2][l] * x[b][l][c] ----------------
__global__ __launch_bounds__(256) void k_dft(const float* __restrict__ x,
                                             const u16* __restrict__ FT,
                                             u16* __restrict__ Z) {
  __shared__ __align__(16) u16 Al[128 * 40];
  __shared__ __align__(16) u16 Bl[128 * 40];
  int b = blockIdx.x >> 3, ct = blockIdx.x & 7;
  int tid = threadIdx.x, lane = tid & 63, w = tid >> 6;
  f32x4 acc[2][8];
#pragma unroll
  for (int i = 0; i < 2; i++)
#pragma unroll
    for (int j = 0; j < 8; j++) acc[i][j] = (f32x4){0.f, 0.f, 0.f, 0.f};
  int am2 = tid >> 1, ahalf = tid & 1;
  int c = tid & 127, lg = tid >> 7;
  for (int kk = 0; kk < 32; ++kk) {
    {
      const uint4* src = (const uint4*)(FT + am2 * 1024 + kk * 32 + ahalf * 16);
      uint4 v0 = src[0], v1 = src[1];
      uint4* dst = (uint4*)(Al + am2 * 40 + ahalf * 16);
      dst[0] = v0; dst[1] = v1;
    }
    {
      const float* xb = x + ((size_t)b * 1024 + kk * 32) * 1024 + ct * 128 + c;
#pragma unroll
      for (int jj = 0; jj < 4; ++jj) {
        int l0 = lg * 16 + jj * 4;
        float f0 = xb[(size_t)(l0 + 0) * 1024];
        float f1 = xb[(size_t)(l0 + 1) * 1024];
        float f2_ = xb[(size_t)(l0 + 2) * 1024];
        float f3 = xb[(size_t)(l0 + 3) * 1024];
        uint2 p = {pk2(f0, f1), pk2(f2_, f3)};
        *(uint2*)(Bl + c * 40 + l0) = p;
      }
    }
    __syncthreads();
    bf16x8 af[2];
#pragma unroll
    for (int mi = 0; mi < 2; mi++)
      af[mi] = *(const bf16x8*)(Al + (w * 32 + mi * 16 + (lane & 15)) * 40 + 8 * (lane >> 4));
#pragma unroll
    for (int ni = 0; ni < 8; ni++) {
      bf16x8 bf = *(const bf16x8*)(Bl + (ni * 16 + (lane & 15)) * 40 + 8 * (lane >> 4));
#pragma unroll
      for (int mi = 0; mi < 2; mi++) acc[mi][ni] = mfma16(af[mi], bf, acc[mi][ni]);
    }
    __syncthreads();
  }
#pragma unroll
  for (int mi = 0; mi < 2; mi++)
#pragma unroll
    for (int ni = 0; ni < 8; ni++)
#pragma unroll
      for (int r = 0; r < 4; r++) {
        int row = w * 32 + mi * 16 + 4 * (lane >> 4) + r;
        int col = ct * 128 + ni * 16 + (lane & 15);
        Z[((size_t)b * 128 + row) * 1024 + col] = f2b(acc[mi][ni][r]);
      }
}

__global__ __launch_bounds__(256) void k_wqmix(const u16* __restrict__ Zm,
                                               const u16* __restrict__ Wq16,
                                               const float* __restrict__ bq,
                                               u16* __restrict__ XF) {
  int mt = blockIdx.x >> 3, nt = blockIdx.x & 7;
  gemm128<32, true>(Zm, (size_t)mt * 128, 1024, Wq16, nt * 128, XF, (size_t)mt * 128, bq);
}

__global__ __launch_bounds__(256) void k_gmat(const u16* __restrict__ FI2,
                                              const u16* __restrict__ Wo16,
                                              u16* __restrict__ G2) {
  int nt = blockIdx.x;
  gemm128<32, false>(FI2, 0, 1024, Wo16, nt * 128, G2, 0, nullptr);
}

// ------- mode mix per (h,m): complex [32b x 128e] @ [128e x 128o] -> OS2T -------
// OS2T[b][i'=h*128+o][2m] = Re, [2m+1] = Im  (one u32 store per pair)
__global__ __launch_bounds__(256) void k_modemix(const u16* __restrict__ XF,
                                                 const u16* __restrict__ W2r,
                                                 const u16* __restrict__ W2i,
                                                 u16* __restrict__ OS2T) {
  __shared__ __align__(16) u16 XAr[32 * 200], XAi[32 * 200];
  __shared__ __align__(16) u16 Wbr[128 * 40], Wbi[128 * 40];
  int h = blockIdx.x >> 6, m = blockIdx.x & 63;
  int tid = threadIdx.x, lane = tid & 63, w = tid >> 6;
  {
    int bb = tid >> 3, seg = tid & 7;
    int e0 = seg * 16, kc = seg >> 1, off = (seg & 1) * 16;
    const uint4* sr = (const uint4*)(XF + ((size_t)bb * 128 + m) * 1024 + h * 128 + e0);
    const uint4* si = (const uint4*)(XF + ((size_t)bb * 128 + 64 + m) * 1024 + h * 128 + e0);
    uint4* dr = (uint4*)(XAr + bb * 200 + kc * 40 + off);
    uint4* di = (uint4*)(XAi + bb * 200 + kc * 40 + off);
    dr[0] = sr[0]; dr[1] = sr[1];
    di[0] = si[0]; di[1] = si[1];
  }
  f32x4 accR[2][2], accI[2][2];
#pragma unroll
  for (int i = 0; i < 2; i++)
#pragma unroll
    for (int j = 0; j < 2; j++) {
      accR[i][j] = (f32x4){0.f, 0.f, 0.f, 0.f};
      accI[i][j] = (f32x4){0.f, 0.f, 0.f, 0.f};
    }
  for (int kk = 0; kk < 4; ++kk) {
    {
      int o = tid & 127, pr = tid >> 7;
      const u16* src = (pr ? W2i : W2r) + (((size_t)h * 64 + m) * 128 + kk * 32) * 128 + o;
      u16* dst = (pr ? Wbi : Wbr) + o * 40;
#pragma unroll
      for (int jj = 0; jj < 8; ++jj) {
        int e0 = jj * 4;
        u16 s0 = src[(size_t)(e0 + 0) * 128], s1 = src[(size_t)(e0 + 1) * 128];
        u16 s2 = src[(size_t)(e0 + 2) * 128], s3 = src[(size_t)(e0 + 3) * 128];
        *(u64*)(dst + e0) = (u64)s0 | ((u64)s1 << 16) | ((u64)s2 << 32) | ((u64)s3 << 48);
      }
    }
    __syncthreads();
    bf16x8 ar[2], ai_[2], ain[2];
#pragma unroll
    for (int mi = 0; mi < 2; mi++) {
      int bb = mi * 16 + (lane & 15);
      ar[mi] = *(const bf16x8*)(XAr + bb * 200 + kk * 40 + 8 * (lane >> 4));
      ai_[mi] = *(const bf16x8*)(XAi + bb * 200 + kk * 40 + 8 * (lane >> 4));
      u32 t4[4];
      __builtin_memcpy(t4, &ai_[mi], 16);
#pragma unroll
      for (int q = 0; q < 4; q++) t4[q] ^= 0x80008000u;
      __builtin_memcpy(&ain[mi], t4, 16);
    }
#pragma unroll
    for (int ni = 0; ni < 2; ni++) {
      int o = w * 32 + ni * 16 + (lane & 15);
      bf16x8 br = *(const bf16x8*)(Wbr + o * 40 + 8 * (lane >> 4));
      bf16x8 bi = *(const bf16x8*)(Wbi + o * 40 + 8 * (lane >> 4));
#pragma unroll
      for (int mi = 0; mi < 2; mi++) {
        accR[mi][ni] = mfma16(ar[mi], br, accR[mi][ni]);
        accR[mi][ni] = mfma16(ain[mi], bi, accR[mi][ni]);
        accI[mi][ni] = mfma16(ar[mi], bi, accI[mi][ni]);
        accI[mi][ni] = mfma16(ai_[mi], br, accI[mi][ni]);
      }
    }
    __syncthreads();
  }
#pragma unroll
  for (int mi = 0; mi < 2; mi++)
#pragma unroll
    for (int ni = 0; ni < 2; ni++)
#pragma unroll
      for (int rr = 0; rr < 4; rr++) {
        int brow = mi * 16 + 4 * (lane >> 4) + rr;
        int o = w * 32 + ni * 16 + (lane & 15);
        size_t base = (size_t)brow * 131072 + (size_t)(h * 128 + o) * 128;
        *(u32*)(OS2T + base + 2 * m) = pk2(accR[mi][ni][rr], accI[mi][ni][rr]);
      }
}

// ---- fused output GEMM + residual + series_decomp ----
// Per block (b, rt, dt): z rows [r0-16, r0+144) x 64 cols, K=128 GEMM from OS2T/G2,
// + x, then moving-average residual for rows [r0, r0+128). bo cancels exactly.
__global__ __launch_bounds__(256) void k_nxdecomp(const float* __restrict__ x,
                                                  const u16* __restrict__ OS2T,
                                                  const u16* __restrict__ G2,
                                                  float* __restrict__ out) {
  __shared__ __align__(16) u16 SMEM[160 * 136 + 64 * 136];  // 60928 B
  u16* Al = SMEM;
  u16* Bl = SMEM + 160 * 136;
  float* ZT = (float*)SMEM;  // phase-2 alias of Al/Bl region (160*68 f32 = 43520 B)
  int bid = blockIdx.x;
  // XCD grouping: the 16 dt-blocks sharing A rows have bid % 8 == rt -> same XCD
  int rt = bid & 7, dt = (bid >> 3) & 15, b = bid >> 7;
  int r0 = rt * 128, d0 = dt * 64;
  int tid = threadIdx.x, lane = tid & 63, w = tid >> 6;
  int wr = w >> 1, wc = w & 1;
  // stage A: OS2T rows [r0-16, r0+144) clamped (replicate), full K=128
  for (int it = 0; it < 10; ++it) {
    int q = tid + it * 256;  // [0, 2560)
    int row = q >> 4, seg = q & 15;
    int gr = r0 - 16 + row;
    gr = gr < 0 ? 0 : (gr > 1023 ? 1023 : gr);
    *(uint4*)(Al + row * 136 + seg * 8) =
        *(const uint4*)(OS2T + ((size_t)b * 1024 + gr) * 128 + seg * 8);
  }
  // stage B: G2[k][d0+c] -> Bl[c][k]
  {
    int c = tid & 63, lg = tid >> 6;
#pragma unroll
    for (int jj = 0; jj < 8; ++jj) {
      int l0 = lg * 32 + jj * 4;
      const u16* gp = G2 + (size_t)l0 * 1024 + d0 + c;
      u16 s0 = gp[0], s1 = gp[1024], s2 = gp[2048], s3 = gp[3072];
      *(u64*)(Bl + c * 136 + l0) =
          (u64)s0 | ((u64)s1 << 16) | ((u64)s2 << 32) | ((u64)s3 << 48);
    }
  }
  // prefetch x for epilogue (latency hides under MFMA phase)
  float xv[5][2][4];
#pragma unroll
  for (int mi = 0; mi < 5; ++mi)
#pragma unroll
    for (int r = 0; r < 4; ++r) {
      int row = wr * 80 + mi * 16 + 4 * (lane >> 4) + r;
      int gr = r0 - 16 + row;
      gr = gr < 0 ? 0 : (gr > 1023 ? 1023 : gr);
#pragma unroll
      for (int ni = 0; ni < 2; ++ni) {
        int col = wc * 32 + ni * 16 + (lane & 15);
        xv[mi][ni][r] = x[((size_t)b * 1024 + gr) * 1024 + d0 + col];
      }
    }
  f32x4 acc[5][2];
#pragma unroll
  for (int i = 0; i < 5; i++)
#pragma unroll
    for (int j = 0; j < 2; j++) acc[i][j] = (f32x4){0.f, 0.f, 0.f, 0.f};
  __syncthreads();
#pragma unroll
  for (int kk = 0; kk < 4; ++kk) {
    bf16x8 af[5], bf[2];
#pragma unroll
    for (int mi = 0; mi < 5; ++mi)
      af[mi] = *(const bf16x8*)(Al + (wr * 80 + mi * 16 + (lane & 15)) * 136 +
                                kk * 32 + 8 * (lane >> 4));
#pragma unroll
    for (int ni = 0; ni < 2; ++ni)
      bf[ni] = *(const bf16x8*)(Bl + (wc * 32 + ni * 16 + (lane & 15)) * 136 +
                                kk * 32 + 8 * (lane >> 4));
#pragma unroll
    for (int mi = 0; mi < 5; ++mi)
#pragma unroll
      for (int ni = 0; ni < 2; ++ni) acc[mi][ni] = mfma16(af[mi], bf[ni], acc[mi][ni]);
  }
  __syncthreads();  // all LDS reads done before ZT overwrites Al/Bl
#pragma unroll
  for (int mi = 0; mi < 5; ++mi)
#pragma unroll
    for (int ni = 0; ni < 2; ++ni)
#pragma unroll
      for (int r = 0; r < 4; ++r) {
        int row = wr * 80 + mi * 16 + 4 * (lane >> 4) + r;
        int col = wc * 32 + ni * 16 + (lane & 15);
        ZT[row * 68 + col] = acc[mi][ni][r] + xv[mi][ni][r];
      }
  __syncthreads();
  {
    int c = tid & 63, h2 = tid >> 6;
    int j0 = h2 * 32;
    float s = 0.f;
#pragma unroll
    for (int u = 0; u < 25; ++u) s += ZT[(j0 + 4 + u) * 68 + c];
    for (int j = j0; j < j0 + 32; ++j) {
      float center = ZT[(j + 16) * 68 + c];
      out[((size_t)b * 1024 + r0 + j) * 1024 + d0 + c] = center - s * (1.0f / 25.0f);
      if (j < j0 + 31) s += ZT[(j + 29) * 68 + c] - ZT[(j + 4) * 68 + c];
    }
  }
}

extern "C" void kernel_launch(void* const* d_in, const int* in_sizes, int n_in,
                              void* d_out, int out_size, void* d_ws, size_t ws_size,
                              hipStream_t stream) {
  const float* x = (const float*)d_in[0];
  const float* Wq = (const float*)d_in[1];
  const float* bq = (const float*)d_in[2];
  const float* w1r = (const float*)d_in[3];
  const float* w1i = (const float*)d_in[4];
  const float* Wo = (const float*)d_in[5];
  // d_in[6] = bo: cancels exactly in res = z - MA(z) (constant along L, replicate pad)

  char* ws = (char*)d_ws;
  u16* FT = (u16*)(ws + 0x000000);     // 256 KB [128][1024]
  u16* FI2 = (u16*)(ws + 0x040000);    // 256 KB [128][1024] interleaved rows
  u16* Wq16 = (u16*)(ws + 0x080000);   // 2 MB
  u16* Wo16 = (u16*)(ws + 0x280000);   // 2 MB
  u16* G2 = (u16*)(ws + 0x480000);     // 256 KB [128][1024]
  u16* OS2T = (u16*)(ws + 0x4C0000);   // 8.4 MB [b][i'][m2-interleaved]

  // Scratch dead before k_nxdecomp lives in d_out (fully rewritten at the end)
  char* ob = (char*)d_out;
  u16* W2r = (u16*)(ob + 0x0000000);   // 16.8 MB [h][m][e][o]
  u16* W2i = (u16*)(ob + 0x1000000);   // 16.8 MB
  u16* Zm = (u16*)(ob + 0x2000000);    // 8.4 MB [b][m2][1024]
  u16* XF = (u16*)(ob + 0x2800000);    // 8.4 MB [b*128+m2][1024]

  k_prep<<<9216, 256, 0, stream>>>(Wq, Wo, FT, FI2, Wq16, Wo16);
  k_wtrans<<<1024, 256, 0, stream>>>(w1r, w1i, W2r, W2i);
  k_gmat<<<8, 256, 0, stream>>>(FI2, Wo16, G2);
  k_dft<<<256, 256, 0, stream>>>(x, FT, Zm);
  k_wqmix<<<256, 256, 0, stream>>>(Zm, Wq16, bq, XF);
  k_modemix<<<512, 256, 0, stream>>>(XF, W2r, W2i, OS2T);
  k_nxdecomp<<<4096, 256, 0, stream>>>(x, OS2T, G2, (float*)d_out);
}